// Round 9
// baseline (659.027 us; speedup 1.0000x reference)
//
#include <hip/hip_runtime.h>
#include <hip/hip_bf16.h>
#include <math.h>

typedef __bf16 bf16x8 __attribute__((ext_vector_type(8)));
typedef short  s16x8  __attribute__((ext_vector_type(8)));
typedef short  s16x4  __attribute__((ext_vector_type(4)));
typedef float  f32x16 __attribute__((ext_vector_type(16)));
typedef unsigned short u16;

// ---- sizes ----
#define NN 32
#define CC 256
#define HH 56
#define WW 56
#define HP 68            // padded spatial (6 halo each side)
#define XP2_BYTES 75759616ull            // 32*68*68*256*2
#define XP2_OFF 0ull
#define WT3_OFF 75759616ull              // 200*16384 B = 3276800
#define T1_OFF  79036416ull              // 32*256*56*4 = 1835008
#define T9_OFF  80871424ull              // 32*56*56*4

__device__ inline u16 f2bf(float f) {
    unsigned int u = __builtin_bit_cast(unsigned int, f);
    u = (u + 0x7fffu + ((u >> 16) & 1u)) >> 16;   // RNE
    return (u16)u;
}

__device__ inline void gl_lds16(const char* g, char* l) {
    __builtin_amdgcn_global_load_lds(
        (const __attribute__((address_space(1))) unsigned int*)g,
        (__attribute__((address_space(3))) unsigned int*)l, 16, 0, 0);
}

// ---- zero only the halo of xp2 (interior fully written by prep) ----
__global__ void zero_halo(u16* __restrict__ xp2) {
    const int total = NN * 1488 * 32;           // 16B chunks
    int i = blockIdx.x * blockDim.x + threadIdx.x;
    const int stride = gridDim.x * blockDim.x;
    uint4 z; z.x = z.y = z.z = z.w = 0u;
    for (; i < total; i += stride) {
        int chunk = i & 31;
        int pid = i >> 5;
        int n = pid / 1488;
        int hp = pid - n * 1488;
        int row, col;
        if (hp < 816) { int r = hp / 68; col = hp - r * 68; row = (r < 6) ? r : r + 56; }
        else { int hq = hp - 816; int rr = hq / 12; int c12 = hq - rr * 12;
               row = 6 + rr; col = (c12 < 6) ? c12 : c12 + 56; }
        *(uint4*)((char*)xp2 + ((((size_t)n * HP + row) * HP + col) * 512) + chunk * 16) = z;
    }
}

// ---- pack w7 -> wt3, cout-group-split 32x32x16 fragment order ----
// per kn (32 cins) block of 16KB: [cg(2)][ks(2)][rb(4)][lane(64)][8 u16]
// c_out = cg*128 + rb*32 + (lane&31); cin-in-32 = ks*16 + (lane>>5)*8 + j.
__global__ __launch_bounds__(256)
void pack_w(const float* __restrict__ w7, u16* __restrict__ wt3) {
    int idx = blockIdx.x * 256 + threadIdx.x;    // 256*6400 total
    int c_out = idx / 6400;
    int k = idx - c_out * 6400;
    int cin = k / 25;
    int tap = k - cin * 25;
    int kn = tap * 8 + (cin >> 5);
    int c5 = cin & 31;
    int ks = c5 >> 4, lhi = (c5 >> 3) & 1, j = c5 & 7;
    int lane = lhi * 32 + (c_out & 31);
    int cg = c_out >> 7, rb = (c_out >> 5) & 3;
    wt3[(size_t)kn * 8192 + cg * 4096 + ks * 2048 + rb * 512 + lane * 8 + j] = f2bf(w7[idx]);
}

// ---- fused prep: t1 (row max) + t9 (softmax of einsum) + pack x ----
// (r6 winner, unchanged)
__global__ __launch_bounds__(256)
void prep(const float* __restrict__ x, const float* __restrict__ w6,
          float* __restrict__ t1, float* __restrict__ t9,
          u16* __restrict__ xp2) {
    const int n = blockIdx.x / HH;
    const int h = blockIdx.x % HH;
    const int tid = threadIdx.x;
    const int lane = tid & 63;
    const int wid = tid >> 6;
    const int g16 = lane >> 4;        // 0..3: c-subrow within wave
    const int wq  = lane & 15;        // w-quad, active if <14
    const bool act = wq < 14;
    __shared__ u16 xbuf[64 * 60];
    __shared__ float sacc[16][56];
    const float* xrow = x + ((size_t)(n * CC) * HH + h) * WW;
    u16* dst = xp2 + (((size_t)n * HP + h + 6) * HP + 6) * CC;
    float a0 = 0.f, a1 = 0.f, a2 = 0.f, a3 = 0.f;
    for (int g = 0; g < 4; ++g) {
        if (g) __syncthreads();
#pragma unroll
        for (int it = 0; it < 4; ++it) {
            const int cl = wid * 16 + it * 4 + g16;
            const int c  = g * 64 + cl;
            float4 v = make_float4(0.f, 0.f, 0.f, 0.f);
            if (act) v = *(const float4*)(xrow + (size_t)c * (HH * WW) + wq * 4);
            if (act) {
                s16x4 pk;
                pk[0] = (short)f2bf(v.x); pk[1] = (short)f2bf(v.y);
                pk[2] = (short)f2bf(v.z); pk[3] = (short)f2bf(v.w);
                *(s16x4*)(xbuf + cl * 60 + wq * 4) = pk;
            }
            float m = act ? fmaxf(fmaxf(v.x, v.y), fmaxf(v.z, v.w)) : -INFINITY;
#pragma unroll
            for (int off = 8; off > 0; off >>= 1)
                m = fmaxf(m, __shfl_xor(m, off));
            if (wq == 0) t1[(size_t)(n * CC + c) * HH + h] = m;
            if (act) {
                const float wc = w6[c];
                a0 += wc * (1.f - 2.f * __builtin_amdgcn_rcpf(__expf(2.f * fmaxf(v.x, 0.f)) + 1.f));
                a1 += wc * (1.f - 2.f * __builtin_amdgcn_rcpf(__expf(2.f * fmaxf(v.y, 0.f)) + 1.f));
                a2 += wc * (1.f - 2.f * __builtin_amdgcn_rcpf(__expf(2.f * fmaxf(v.z, 0.f)) + 1.f));
                a3 += wc * (1.f - 2.f * __builtin_amdgcn_rcpf(__expf(2.f * fmaxf(v.w, 0.f)) + 1.f));
            }
        }
        __syncthreads();
        for (int id = tid; id < WW * 8; id += 256) {
            int p = id >> 3, ch8 = id & 7;
            s16x8 pk;
#pragma unroll
            for (int j = 0; j < 8; ++j)
                pk[j] = (short)xbuf[(ch8 * 8 + j) * 60 + p];
            *(s16x8*)(dst + (size_t)p * CC + g * 64 + ch8 * 8) = pk;
        }
    }
    if (act) {
        float* sl = sacc[wid * 4 + g16];
        sl[wq * 4 + 0] = a0; sl[wq * 4 + 1] = a1;
        sl[wq * 4 + 2] = a2; sl[wq * 4 + 3] = a3;
    }
    __syncthreads();
    if (wid == 0) {
        const bool valid = lane < WW;
        float s = 0.f;
        if (valid) {
#pragma unroll
            for (int gi = 0; gi < 16; ++gi) s += sacc[gi][lane];
        }
        float sm = valid ? s : -INFINITY;
        float mx = sm;
#pragma unroll
        for (int off = 32; off > 0; off >>= 1)
            mx = fmaxf(mx, __shfl_xor(mx, off));
        float e = valid ? expf(s - mx) : 0.f;
        float tot = e;
#pragma unroll
        for (int off = 32; off > 0; off >>= 1)
            tot += __shfl_xor(tot, off);
        if (valid) t9[((size_t)n * HH + h) * WW + lane] = e / tot;
    }
}

// ---- main: implicit GEMM, 128 couts x 128 pos per block, BK=32 ----
// OCCUPANCY RESTRUCTURE: 256 thr = 4 waves (2M x 2N), wave 64x64, acc =
// 4 x f32x16 = 64 AGPR -> ~3 waves/SIMD by regs; LDS 3 bufs x 16KB = 48KB
// -> 3 blocks/CU. Prior 256^2/8-wave shape was locked at 1 block/CU (acc
// 128/lane) and stuck at 400-450us across ALL schedule variants (r3/r4/r7):
// barrier convoys had no co-resident block to fill them. Grid 1568 (6.1
// blocks/CU) also removes the 392-block 2.0-round quantization (76.6% fill).
// Proven pieces kept: fragment-order conflict-free LDS, single barrier +
// counted vmcnt(4)/tile (depth-2 prefetch), r4 stage/read/MFMA interleave,
// setprio, XCD swizzle (1568=8*196; cg fastest -> cg-pairs share B in L2).
__global__ __launch_bounds__(256, 3)
void conv_main(const char* __restrict__ xp2b, const char* __restrict__ wt3b,
               const float* __restrict__ x, const float* __restrict__ t1,
               const float* __restrict__ t9, float* __restrict__ out) {
    extern __shared__ __align__(16) char smem[];   // 3 bufs x 16KB = 48KB
    const int bid = blockIdx.x;
    const int blk = (bid & 7) * 196 + (bid >> 3);   // XCD-aware swizzle
    const int cg  = blk & 1;          // cout group: [cg*128, +128)
    const int pt  = blk >> 1;         // pos tile: [pt*128, +128)
    const int tid = threadIdx.x;
    const int wid = tid >> 6;         // 0..3
    const int lane = tid & 63;
    const int l31 = lane & 31;
    const int lhi = lane >> 5;
    const int wr = wid >> 1;          // cout 64-block within 128
    const int wc = wid & 1;           // pos 64-block within 128

    // B gather: wave wid stages units {2*wid, 2*wid+1}; unit u = ks*4+cb
    // (ks = wid>>1, cb = (2*wid+i)&3). LDS slot lane holds pos cb*32+l31,
    // k-bytes ks*32 + lhi*16.
    unsigned vb[2];
#pragma unroll
    for (int i = 0; i < 2; ++i) {
        int p = pt * 128 + ((2 * wid + i) & 3) * 32 + l31;
        int n = p / (HH * WW);
        int rem = p - n * (HH * WW);
        int hh = rem / WW;
        int ww = rem - hh * WW;
        vb[i] = ((((unsigned)n * HP + hh + 6) * HP) + ww + 6) * 512
                + (wid >> 1) * 32 + lhi * 16;
    }

    // t2 may exceed 199 (tail dummies wrap; those buffers are never read)
    auto stageA = [&](int t2, int bi, int i) {
        const int kn = (t2 < 200) ? t2 : (t2 - 200);
        const unsigned o = (2 * wid + i) * 1024 + lane * 16;
        gl_lds16(wt3b + (size_t)kn * 16384 + cg * 8192 + o,
                 smem + bi * 16384 + o);
    };
    auto stageB = [&](int t2, int bi, int i) {
        const int kn = (t2 < 200) ? t2 : (t2 - 200);
        const int tap = kn >> 3, ch = kn & 7;
        const char* gb = xp2b +
            (ptrdiff_t)((tap / 5) * 3 - 6) * (HP * 512) +
            (ptrdiff_t)((tap % 5) * 3 - 6) * 512 + ch * 64 + vb[i];
        gl_lds16(gb, smem + bi * 16384 + 8192 + (2 * wid + i) * 1024 + lane * 16);
    };

    f32x16 acc[2][2];
#pragma unroll
    for (int mi = 0; mi < 2; ++mi)
#pragma unroll
        for (int nb = 0; nb < 2; ++nb)
#pragma unroll
            for (int r = 0; r < 16; ++r)
                acc[mi][nb][r] = 0.f;

    // frag offsets (wave-contiguous 1KB reads -> conflict-free)
    const int aoff = wr * 2048 + lane * 16;           // + ks*4096 + mi*1024
    const int boff = 8192 + wc * 2048 + lane * 16;    // + ks*4096 + nb*1024

    // prologue: stage tiles 0,1 (8 quanta); gate tile 0 landed
    stageA(0, 0, 0); stageB(0, 0, 0); stageA(0, 0, 1); stageB(0, 0, 1);
    stageA(1, 1, 0); stageB(1, 1, 0); stageA(1, 1, 1); stageB(1, 1, 1);
    asm volatile("s_waitcnt vmcnt(4)" ::: "memory");
    __builtin_amdgcn_s_barrier();

    int bc = 0, bs = 2;   // compute buf (t%3), stage buf ((t+2)%3)
    for (int t = 0; t < 200; ++t) {
        const char* bp = smem + bc * 16384;
        bf16x8 av0, av1, bv0, bv1;
#pragma unroll
        for (int ks = 0; ks < 2; ++ks) {
            stageA(t + 2, bs, ks); stageB(t + 2, bs, ks);
            av0 = *(const bf16x8*)(const void*)(bp + aoff + ks * 4096);
            av1 = *(const bf16x8*)(const void*)(bp + aoff + ks * 4096 + 1024);
            bv0 = *(const bf16x8*)(const void*)(bp + boff + ks * 4096);
            bv1 = *(const bf16x8*)(const void*)(bp + boff + ks * 4096 + 1024);
            __builtin_amdgcn_s_setprio(1);
            acc[0][0] = __builtin_amdgcn_mfma_f32_32x32x16_bf16(av0, bv0, acc[0][0], 0, 0, 0);
            acc[0][1] = __builtin_amdgcn_mfma_f32_32x32x16_bf16(av0, bv1, acc[0][1], 0, 0, 0);
            acc[1][0] = __builtin_amdgcn_mfma_f32_32x32x16_bf16(av1, bv0, acc[1][0], 0, 0, 0);
            acc[1][1] = __builtin_amdgcn_mfma_f32_32x32x16_bf16(av1, bv1, acc[1][1], 0, 0, 0);
            __builtin_amdgcn_s_setprio(0);
        }
        // counted wait: leaves tile t+2's 4 quanta in flight; tile t+1 landed
        asm volatile("s_waitcnt vmcnt(4)" ::: "memory");
        __builtin_amdgcn_s_barrier();
        bc = (bc == 2) ? 0 : bc + 1;
        bs = (bs == 2) ? 0 : bs + 1;
    }
    // drain: in-flight DMA must not outlive this block's LDS
    asm volatile("s_waitcnt vmcnt(0)" ::: "memory");

    // epilogue: out = t1 - (t9 * roll(x,2,h) + x * t7)
    // C/D map (m74/m101): col = lane&31, row = (r&3) + 8*(r>>2) + 4*(lane>>5)
#pragma unroll
    for (int nb = 0; nb < 2; ++nb) {
        const int p = pt * 128 + wc * 64 + nb * 32 + l31;
        const int n = p / (HH * WW);
        const int rem = p - n * (HH * WW);
        const int h = rem / WW;
        const int w = rem - h * WW;
        const float t9v = t9[((size_t)n * HH + h) * WW + w];
        const int hprev = (h >= 2) ? (h - 2) : (h + HH - 2);
#pragma unroll
        for (int mi = 0; mi < 2; ++mi) {
            const int c0 = cg * 128 + wr * 64 + mi * 32 + 4 * lhi;
#pragma unroll
            for (int r = 0; r < 16; ++r) {
                const int c = c0 + (r & 3) + 8 * (r >> 2);
                const size_t rowi = (size_t)(n * CC + c) * HH;
                const float t1v = t1[rowi + h];
                const float xv = x[(rowi + h) * WW + w];
                const float xr = x[(rowi + hprev) * WW + w];
                out[(rowi + h) * WW + w] = t1v - (t9v * xr + xv * acc[mi][nb][r]);
            }
        }
    }
}

extern "C" void kernel_launch(void* const* d_in, const int* in_sizes, int n_in,
                              void* d_out, int out_size, void* d_ws, size_t ws_size,
                              hipStream_t stream) {
    const float* x  = (const float*)d_in[0];
    const float* w6 = (const float*)d_in[1];
    const float* w7 = (const float*)d_in[2];
    float* out = (float*)d_out;
    char* ws = (char*)d_ws;
    u16*   xp2 = (u16*)(ws + XP2_OFF);
    u16*   wt3 = (u16*)(ws + WT3_OFF);
    float* t1  = (float*)(ws + T1_OFF);
    float* t9  = (float*)(ws + T9_OFF);

    static bool lds_cfg_done = false;
    if (!lds_cfg_done) {
        (void)hipFuncSetAttribute((const void*)conv_main,
                                  hipFuncAttributeMaxDynamicSharedMemorySize,
                                  49152);
        lds_cfg_done = true;
    }

    zero_halo<<<dim3(1024), dim3(256), 0, stream>>>(xp2);
    pack_w<<<dim3(6400), dim3(256), 0, stream>>>(w7, wt3);
    prep<<<dim3(NN * HH), dim3(256), 0, stream>>>(x, w6, t1, t9, xp2);
    conv_main<<<dim3(1568), dim3(256), 49152, stream>>>((const char*)xp2, (const char*)wt3,
                                                        x, t1, t9, out);
}